// Round 4
// baseline (1038.433 us; speedup 1.0000x reference)
//
#include <hip/hip_runtime.h>

#define HW   16384
#define CC   256
#define OT   32      // out-channel tile per block
#define NT   512     // column tile per block
#define KB   8       // k-chunk

// ---------------------------------------------------------------------------
// GEMM1: h[b,o,hw] = sum_c W_proj[o,c] * x[b,c,hw]; fused per-channel sum/sumsq
// ---------------------------------------------------------------------------
__global__ __launch_bounds__(256)
void gu_gemm1(const float* __restrict__ x, const float* __restrict__ Wp,
              float* __restrict__ h, float* __restrict__ psum,
              float* __restrict__ psumsq)
{
    __shared__ float ws[CC][OT];   // 32KB, [c][o]
    __shared__ float xs[KB][NT];   // 16KB

    const int t  = threadIdx.x;
    const int tx = t & 63, ty = t >> 6;
    const int o0 = blockIdx.y * OT;
    const int n0 = blockIdx.x * NT;          // 512 | 16384 -> never straddles images
    const int b  = n0 >> 14;
    const int hw0 = n0 & (HW - 1);
    const float* xb = x + ((size_t)b * CC) * HW + hw0;

    // stage W tile: ws[c][o] = Wp[(o0+o)*CC + c]
    for (int i = t; i < CC * OT; i += 256) {
        int c = i >> 5, o = i & (OT - 1);
        ws[c][o] = Wp[(o0 + o) * CC + c];
    }

    // prefetch k-chunk 0 into regs
    float4 pf[4];
    #pragma unroll
    for (int q = 0; q < 4; ++q) {
        int f = t + 256 * q; int k = f >> 7; int co = (f & 127) << 2;
        pf[q] = *(const float4*)(xb + (size_t)k * HW + co);
    }

    float acc[8][8];
    #pragma unroll
    for (int i = 0; i < 8; ++i)
        #pragma unroll
        for (int j = 0; j < 8; ++j) acc[i][j] = 0.f;

    __syncthreads();
    for (int c0 = 0; c0 < CC; c0 += KB) {
        #pragma unroll
        for (int q = 0; q < 4; ++q) {
            int f = t + 256 * q; int k = f >> 7; int co = (f & 127) << 2;
            *(float4*)&xs[k][co] = pf[q];
        }
        __syncthreads();
        if (c0 + KB < CC) {
            #pragma unroll
            for (int q = 0; q < 4; ++q) {
                int f = t + 256 * q; int k = f >> 7; int co = (f & 127) << 2;
                pf[q] = *(const float4*)(xb + (size_t)(c0 + KB + k) * HW + co);
            }
        }
        #pragma unroll
        for (int k = 0; k < KB; ++k) {
            float4 xa = *(const float4*)&xs[k][tx * 4];
            float4 xc = *(const float4*)&xs[k][256 + tx * 4];
            float4 wa = *(const float4*)&ws[c0 + k][ty * 8];
            float4 wb = *(const float4*)&ws[c0 + k][ty * 8 + 4];
            float xr[8] = {xa.x, xa.y, xa.z, xa.w, xc.x, xc.y, xc.z, xc.w};
            float wr[8] = {wa.x, wa.y, wa.z, wa.w, wb.x, wb.y, wb.z, wb.w};
            #pragma unroll
            for (int i = 0; i < 8; ++i)
                #pragma unroll
                for (int j = 0; j < 8; ++j)
                    acc[i][j] = fmaf(wr[i], xr[j], acc[i][j]);
        }
        __syncthreads();
    }

    // write h (coalesced float4) + per-channel partial stats
    #pragma unroll
    for (int i = 0; i < 8; ++i) {
        float* hp = h + ((size_t)(b * CC + o0 + ty * 8 + i)) * HW + hw0 + tx * 4;
        *(float4*)hp         = make_float4(acc[i][0], acc[i][1], acc[i][2], acc[i][3]);
        *(float4*)(hp + 256) = make_float4(acc[i][4], acc[i][5], acc[i][6], acc[i][7]);
    }
    #pragma unroll
    for (int i = 0; i < 8; ++i) {
        float s = 0.f, q = 0.f;
        #pragma unroll
        for (int j = 0; j < 8; ++j) { s += acc[i][j]; q = fmaf(acc[i][j], acc[i][j], q); }
        #pragma unroll
        for (int off = 1; off < 64; off <<= 1) {
            s += __shfl_xor(s, off);
            q += __shfl_xor(q, off);
        }
        if (tx == 0) {
            atomicAdd(&psum[o0 + ty * 8 + i], s);
            atomicAdd(&psumsq[o0 + ty * 8 + i], q);
        }
    }
}

// ---------------------------------------------------------------------------
// BN finalize: a = gamma*rsqrt(var+eps), d = beta - mu*a
// ---------------------------------------------------------------------------
__global__ void gu_bnfin(const float* __restrict__ psum, const float* __restrict__ psumsq,
                         const float* __restrict__ gamma, const float* __restrict__ beta,
                         float* __restrict__ avec, float* __restrict__ dvec)
{
    int c = threadIdx.x;
    const float invN = 1.f / 131072.f;
    float mu  = psum[c] * invN;
    float var = psumsq[c] * invN - mu * mu;
    float a   = gamma[c] * rsqrtf(var + 1e-5f);
    avec[c] = a;
    dvec[c] = beta[c] - mu * a;
}

// ---------------------------------------------------------------------------
// Projection pass: mean/logvar proj, prob_x, 50-sample sigmoid variance -> u0
// one position per thread, 512 blocks x 256 threads
// ---------------------------------------------------------------------------
__global__ __launch_bounds__(256)
void gu_proj(const float* __restrict__ h, const float* __restrict__ Wm,
             const float* __restrict__ Wsd, const float* __restrict__ avec,
             const float* __restrict__ dvec, const float* __restrict__ eps1,
             const float* __restrict__ eps50, float* __restrict__ prob_x,
             float* __restrict__ u0)
{
    __shared__ float s_a[CC], s_d[CC], s_m[CC], s_v[CC];
    int t = threadIdx.x;
    s_a[t] = avec[t]; s_d[t] = dvec[t]; s_m[t] = Wm[t]; s_v[t] = Wsd[t];
    __syncthreads();

    int p  = blockIdx.x * 256 + t;     // 0..131071
    int b  = p >> 14;
    int hw = p & (HW - 1);
    const float* hb = h + (size_t)b * CC * HW + hw;

    float mp = 0.f, lp = 0.f;
    #pragma unroll 8
    for (int c = 0; c < CC; ++c) {
        float v = hb[(size_t)c * HW];
        float r = fmaxf(fmaf(s_a[c], v, s_d[c]), 0.f);
        mp = fmaf(s_m[c], r, mp);
        lp = fmaf(s_v[c], r, lp);
    }
    float std = expf(0.5f * lp);
    prob_x[p] = fmaf(eps1[p], std, mp);

    const float* e5 = eps50 + (size_t)b * 50 * HW + hw;
    double s = 0.0, q = 0.0;
    #pragma unroll 5
    for (int k = 0; k < 50; ++k) {
        float z = fmaf(e5[(size_t)k * HW], std, mp);
        float pr = 1.f / (1.f + expf(-z));
        s += (double)pr;
        q += (double)pr * (double)pr;
    }
    u0[p] = (float)((q - s * s * (1.0 / 50.0)) * (1.0 / 49.0));
}

// ---------------------------------------------------------------------------
// Box filter x3 (separable 7x7, zero pad) per image + global min/max atomics
// 8 blocks (one per image), 1024 threads, image held in 64KB LDS
// ---------------------------------------------------------------------------
__global__ __launch_bounds__(1024)
void gu_box(const float* __restrict__ u0, float* __restrict__ u3,
            unsigned* __restrict__ mnb, unsigned* __restrict__ mxb)
{
    __shared__ float A[HW];   // exactly 64KB
    int b = blockIdx.x, t = threadIdx.x;
    const float* src = u0 + (size_t)b * HW;
    for (int i = t; i < HW; i += 1024) A[i] = src[i];
    __syncthreads();

    float tmp[16];
    for (int pass = 0; pass < 3; ++pass) {
        // horizontal (zero pad)
        #pragma unroll
        for (int ii = 0; ii < 16; ++ii) {
            int i = t + ii * 1024;
            int r = i >> 7, c = i & 127;
            float s = 0.f;
            #pragma unroll
            for (int d = -3; d <= 3; ++d) {
                int cc = c + d;
                if (cc >= 0 && cc < 128) s += A[(r << 7) + cc];
            }
            tmp[ii] = s;
        }
        __syncthreads();
        #pragma unroll
        for (int ii = 0; ii < 16; ++ii) A[t + ii * 1024] = tmp[ii];
        __syncthreads();
        // vertical (zero pad)
        #pragma unroll
        for (int ii = 0; ii < 16; ++ii) {
            int i = t + ii * 1024;
            int r = i >> 7, c = i & 127;
            float s = 0.f;
            #pragma unroll
            for (int d = -3; d <= 3; ++d) {
                int rr = r + d;
                if (rr >= 0 && rr < 128) s += A[(rr << 7) + c];
            }
            tmp[ii] = s;
        }
        __syncthreads();
        #pragma unroll
        for (int ii = 0; ii < 16; ++ii) A[t + ii * 1024] = tmp[ii];
        __syncthreads();
    }

    float mn = 3.4e38f, mx = 0.f;
    for (int i = t; i < HW; i += 1024) {
        float v = A[i];
        u3[(size_t)b * HW + i] = v;
        mn = fminf(mn, v); mx = fmaxf(mx, v);
    }
    #pragma unroll
    for (int off = 1; off < 64; off <<= 1) {
        mn = fminf(mn, __shfl_xor(mn, off));
        mx = fmaxf(mx, __shfl_xor(mx, off));
    }
    if ((t & 63) == 0) {   // u >= 0 -> uint order == float order
        atomicMin(mnb, __float_as_uint(mn));
        atomicMax(mxb, __float_as_uint(mx));
    }
}

// ---------------------------------------------------------------------------
// GEMM2: residual = W_conv * relu(a*h+d) + b_conv, scaled by (1-un)*(un<ru)
// BN+ReLU applied during LDS staging; mask/scale in epilogue
// ---------------------------------------------------------------------------
__global__ __launch_bounds__(256)
void gu_gemm2(const float* __restrict__ h, const float* __restrict__ Wc,
              const float* __restrict__ bconv, const float* __restrict__ avec,
              const float* __restrict__ dvec, const float* __restrict__ u3,
              const unsigned* __restrict__ mnb, const unsigned* __restrict__ mxb,
              const float* __restrict__ ru, float* __restrict__ outr)
{
    __shared__ float ws[CC][OT];
    __shared__ float xs[KB][NT];
    __shared__ float sa[CC], sd[CC];

    const int t  = threadIdx.x;
    const int tx = t & 63, ty = t >> 6;
    const int o0 = blockIdx.y * OT;
    const int n0 = blockIdx.x * NT;
    const int b  = n0 >> 14;
    const int hw0 = n0 & (HW - 1);
    const float* xb = h + ((size_t)b * CC) * HW + hw0;

    sa[t] = avec[t]; sd[t] = dvec[t];
    for (int i = t; i < CC * OT; i += 256) {
        int c = i >> 5, o = i & (OT - 1);
        ws[c][o] = Wc[(o0 + o) * CC + c];
    }

    float4 pf[4];
    #pragma unroll
    for (int q = 0; q < 4; ++q) {
        int f = t + 256 * q; int k = f >> 7; int co = (f & 127) << 2;
        pf[q] = *(const float4*)(xb + (size_t)k * HW + co);
    }

    float acc[8][8];
    #pragma unroll
    for (int i = 0; i < 8; ++i)
        #pragma unroll
        for (int j = 0; j < 8; ++j) acc[i][j] = 0.f;

    __syncthreads();
    for (int c0 = 0; c0 < CC; c0 += KB) {
        #pragma unroll
        for (int q = 0; q < 4; ++q) {
            int f = t + 256 * q; int k = f >> 7; int co = (f & 127) << 2;
            float a = sa[c0 + k], d = sd[c0 + k];
            float4 v = pf[q];
            v.x = fmaxf(fmaf(a, v.x, d), 0.f);
            v.y = fmaxf(fmaf(a, v.y, d), 0.f);
            v.z = fmaxf(fmaf(a, v.z, d), 0.f);
            v.w = fmaxf(fmaf(a, v.w, d), 0.f);
            *(float4*)&xs[k][co] = v;
        }
        __syncthreads();
        if (c0 + KB < CC) {
            #pragma unroll
            for (int q = 0; q < 4; ++q) {
                int f = t + 256 * q; int k = f >> 7; int co = (f & 127) << 2;
                pf[q] = *(const float4*)(xb + (size_t)(c0 + KB + k) * HW + co);
            }
        }
        #pragma unroll
        for (int k = 0; k < KB; ++k) {
            float4 xa = *(const float4*)&xs[k][tx * 4];
            float4 xc = *(const float4*)&xs[k][256 + tx * 4];
            float4 wa = *(const float4*)&ws[c0 + k][ty * 8];
            float4 wb = *(const float4*)&ws[c0 + k][ty * 8 + 4];
            float xr[8] = {xa.x, xa.y, xa.z, xa.w, xc.x, xc.y, xc.z, xc.w};
            float wr[8] = {wa.x, wa.y, wa.z, wa.w, wb.x, wb.y, wb.z, wb.w};
            #pragma unroll
            for (int i = 0; i < 8; ++i)
                #pragma unroll
                for (int j = 0; j < 8; ++j)
                    acc[i][j] = fmaf(wr[i], xr[j], acc[i][j]);
        }
        __syncthreads();
    }

    // epilogue: per-column scale = (un < ru) ? (1-un) : 0
    // NOTE: true IEEE division to match JAX's (u-mn)/(mx-mn) bit-for-bit at
    // the mask threshold (mul-by-reciprocal shifts u by ~1e-7 -> pixel flips).
    float mn = __uint_as_float(*mnb);
    float mx = __uint_as_float(*mxb);
    float den = mx - mn;
    const float* u3b = u3 + (size_t)b * HW + hw0 + tx * 4;
    const float* rub = ru + (size_t)b * HW + hw0 + tx * 4;
    float sc[8];
    #pragma unroll
    for (int j = 0; j < 8; ++j) {
        int off = (j < 4) ? j : 256 + (j - 4);
        float un = (u3b[off] - mn) / den;
        sc[j] = (un < rub[off]) ? (1.f - un) : 0.f;
    }
    #pragma unroll
    for (int i = 0; i < 8; ++i) {
        float bc = bconv[o0 + ty * 8 + i];
        float* op = outr + ((size_t)(b * CC + o0 + ty * 8 + i)) * HW + hw0 + tx * 4;
        *(float4*)op = make_float4((acc[i][0] + bc) * sc[0], (acc[i][1] + bc) * sc[1],
                                   (acc[i][2] + bc) * sc[2], (acc[i][3] + bc) * sc[3]);
        *(float4*)(op + 256) = make_float4((acc[i][4] + bc) * sc[4], (acc[i][5] + bc) * sc[5],
                                           (acc[i][6] + bc) * sc[6], (acc[i][7] + bc) * sc[7]);
    }
}

// ---------------------------------------------------------------------------
extern "C" void kernel_launch(void* const* d_in, const int* in_sizes, int n_in,
                              void* d_out, int out_size, void* d_ws, size_t ws_size,
                              hipStream_t stream)
{
    const float* x     = (const float*)d_in[0];
    const float* Wp    = (const float*)d_in[1];
    const float* gamma = (const float*)d_in[2];
    const float* beta  = (const float*)d_in[3];
    const float* Wc    = (const float*)d_in[4];
    const float* bconv = (const float*)d_in[5];
    const float* Wm    = (const float*)d_in[6];
    const float* Wsd   = (const float*)d_in[7];
    const float* eps1  = (const float*)d_in[8];
    const float* eps50 = (const float*)d_in[9];
    const float* ru    = (const float*)d_in[10];

    float* outr = (float*)d_out;                    // residual: 8*256*128*128
    float* outp = outr + (size_t)33554432;          // prob_x:   8*128*128

    float* ws = (float*)d_ws;
    float* h  = ws;                                  // 33,554,432 floats (134MB)
    const size_t S = (size_t)33554432;
    float*    psum   = ws + S;                       // 256
    float*    psumsq = ws + S + 256;                 // 256
    float*    avec   = ws + S + 512;                 // 256
    float*    dvec   = ws + S + 768;                 // 256
    unsigned* mnb    = (unsigned*)(ws + S + 1024);
    unsigned* mxb    = (unsigned*)(ws + S + 1025);
    float*    u0     = ws + S + 2048;                // 131072
    float*    u3     = u0 + 131072;                  // 131072

    hipMemsetAsync(psum, 0, 512 * sizeof(float), stream);  // psum + psumsq
    hipMemsetAsync(mnb, 0x7f, 4, stream);                   // 0x7f7f7f7f ~ +3.39e38
    hipMemsetAsync(mxb, 0, 4, stream);

    gu_gemm1<<<dim3(256, 8), 256, 0, stream>>>(x, Wp, h, psum, psumsq);
    gu_bnfin<<<1, 256, 0, stream>>>(psum, psumsq, gamma, beta, avec, dvec);
    gu_proj<<<512, 256, 0, stream>>>(h, Wm, Wsd, avec, dvec, eps1, eps50, outp, u0);
    gu_box<<<8, 1024, 0, stream>>>(u0, u3, mnb, mxb);
    gu_gemm2<<<dim3(256, 8), 256, 0, stream>>>(h, Wc, bconv, avec, dvec, u3, mnb, mxb, ru, outr);
}

// Round 5
// 1014.242 us; speedup vs baseline: 1.0239x; 1.0239x over previous
//
#include <hip/hip_runtime.h>

#define HW   16384
#define CC   256
#define OT   32      // out-channel tile per block
#define NT   512     // column tile per block
#define KB   8       // k-chunk

// ---------------------------------------------------------------------------
// GEMM1: h[b,o,hw] = sum_c W_proj[o,c] * x[b,c,hw]; fused per-channel sum/sumsq
// W read via scalar path (readfirstlane -> uniform -> s_load), x via LDS dbuf.
// ---------------------------------------------------------------------------
__global__ __launch_bounds__(256)
void gu_gemm1(const float* __restrict__ x, const float* __restrict__ Wp,
              float* __restrict__ h, float* __restrict__ psum,
              float* __restrict__ psumsq)
{
    __shared__ float xs[2][KB][NT];   // 32KB double-buffered x tile

    const int t  = threadIdx.x;
    const int tx = t & 63, ty = t >> 6;
    const int tyu = __builtin_amdgcn_readfirstlane(ty);   // wave-uniform
    const int o0 = blockIdx.y * OT;
    const int n0 = blockIdx.x * NT;          // 512 | 16384 -> never straddles images
    const int b  = n0 >> 14;
    const int hw0 = n0 & (HW - 1);
    const float* xb = x + ((size_t)b * CC) * HW + hw0;
    const float* Wb = Wp + (size_t)(o0 + tyu * 8) * CC;   // 8 rows for this wave

    // prefetch k-chunk 0 into regs
    float4 pf[4];
    #pragma unroll
    for (int q = 0; q < 4; ++q) {
        int f = t + 256 * q; int k = f >> 7; int co = (f & 127) << 2;
        pf[q] = *(const float4*)(xb + (size_t)k * HW + co);
    }

    float acc[8][8];
    #pragma unroll
    for (int i = 0; i < 8; ++i)
        #pragma unroll
        for (int j = 0; j < 8; ++j) acc[i][j] = 0.f;

    int wb = 0;
    for (int c0 = 0; c0 < CC; c0 += KB) {
        // write current chunk to LDS buffer wb
        #pragma unroll
        for (int q = 0; q < 4; ++q) {
            int f = t + 256 * q; int k = f >> 7; int co = (f & 127) << 2;
            *(float4*)&xs[wb][k][co] = pf[q];
        }
        // issue prefetch of next chunk
        if (c0 + KB < CC) {
            #pragma unroll
            for (int q = 0; q < 4; ++q) {
                int f = t + 256 * q; int k = f >> 7; int co = (f & 127) << 2;
                pf[q] = *(const float4*)(xb + (size_t)(c0 + KB + k) * HW + co);
            }
        }
        __syncthreads();
        // compute over 8 k's in two 4-k halves (32 scalar W values live at a time)
        #pragma unroll
        for (int half = 0; half < 2; ++half) {
            float4 wq[8];
            #pragma unroll
            for (int i = 0; i < 8; ++i)
                wq[i] = *(const float4*)(Wb + (size_t)i * CC + c0 + half * 4);
            #pragma unroll
            for (int kk = 0; kk < 4; ++kk) {
                int k = half * 4 + kk;
                float4 xa = *(const float4*)&xs[wb][k][tx * 4];
                float4 xc = *(const float4*)&xs[wb][k][256 + tx * 4];
                #pragma unroll
                for (int i = 0; i < 8; ++i) {
                    float w = ((const float*)&wq[i])[kk];
                    acc[i][0] = fmaf(w, xa.x, acc[i][0]);
                    acc[i][1] = fmaf(w, xa.y, acc[i][1]);
                    acc[i][2] = fmaf(w, xa.z, acc[i][2]);
                    acc[i][3] = fmaf(w, xa.w, acc[i][3]);
                    acc[i][4] = fmaf(w, xc.x, acc[i][4]);
                    acc[i][5] = fmaf(w, xc.y, acc[i][5]);
                    acc[i][6] = fmaf(w, xc.z, acc[i][6]);
                    acc[i][7] = fmaf(w, xc.w, acc[i][7]);
                }
            }
        }
        __syncthreads();
        wb ^= 1;
    }

    // write h (coalesced float4) + per-channel partial stats
    #pragma unroll
    for (int i = 0; i < 8; ++i) {
        float* hp = h + ((size_t)(b * CC + o0 + ty * 8 + i)) * HW + hw0 + tx * 4;
        *(float4*)hp         = make_float4(acc[i][0], acc[i][1], acc[i][2], acc[i][3]);
        *(float4*)(hp + 256) = make_float4(acc[i][4], acc[i][5], acc[i][6], acc[i][7]);
    }
    #pragma unroll
    for (int i = 0; i < 8; ++i) {
        float s = 0.f, q = 0.f;
        #pragma unroll
        for (int j = 0; j < 8; ++j) { s += acc[i][j]; q = fmaf(acc[i][j], acc[i][j], q); }
        #pragma unroll
        for (int off = 1; off < 64; off <<= 1) {
            s += __shfl_xor(s, off);
            q += __shfl_xor(q, off);
        }
        if (tx == 0) {
            atomicAdd(&psum[o0 + ty * 8 + i], s);
            atomicAdd(&psumsq[o0 + ty * 8 + i], q);
        }
    }
}

// ---------------------------------------------------------------------------
// BN finalize: a = gamma*rsqrt(var+eps), d = beta - mu*a
// ---------------------------------------------------------------------------
__global__ void gu_bnfin(const float* __restrict__ psum, const float* __restrict__ psumsq,
                         const float* __restrict__ gamma, const float* __restrict__ beta,
                         float* __restrict__ avec, float* __restrict__ dvec)
{
    int c = threadIdx.x;
    const float invN = 1.f / 131072.f;
    float mu  = psum[c] * invN;
    float var = psumsq[c] * invN - mu * mu;
    float a   = gamma[c] * rsqrtf(var + 1e-5f);
    avec[c] = a;
    dvec[c] = beta[c] - mu * a;
}

// ---------------------------------------------------------------------------
// Projection pass: mean/logvar proj, prob_x, 50-sample sigmoid variance -> u0
// ---------------------------------------------------------------------------
__global__ __launch_bounds__(256)
void gu_proj(const float* __restrict__ h, const float* __restrict__ Wm,
             const float* __restrict__ Wsd, const float* __restrict__ avec,
             const float* __restrict__ dvec, const float* __restrict__ eps1,
             const float* __restrict__ eps50, float* __restrict__ prob_x,
             float* __restrict__ u0)
{
    __shared__ float s_a[CC], s_d[CC], s_m[CC], s_v[CC];
    int t = threadIdx.x;
    s_a[t] = avec[t]; s_d[t] = dvec[t]; s_m[t] = Wm[t]; s_v[t] = Wsd[t];
    __syncthreads();

    int p  = blockIdx.x * 256 + t;     // 0..131071
    int b  = p >> 14;
    int hw = p & (HW - 1);
    const float* hb = h + (size_t)b * CC * HW + hw;

    float mp = 0.f, lp = 0.f;
    #pragma unroll 8
    for (int c = 0; c < CC; ++c) {
        float v = hb[(size_t)c * HW];
        float r = fmaxf(fmaf(s_a[c], v, s_d[c]), 0.f);
        mp = fmaf(s_m[c], r, mp);
        lp = fmaf(s_v[c], r, lp);
    }
    float std = expf(0.5f * lp);
    prob_x[p] = fmaf(eps1[p], std, mp);

    const float* e5 = eps50 + (size_t)b * 50 * HW + hw;
    double s = 0.0, q = 0.0;
    #pragma unroll 5
    for (int k = 0; k < 50; ++k) {
        float z = fmaf(e5[(size_t)k * HW], std, mp);
        float pr = 1.f / (1.f + expf(-z));
        s += (double)pr;
        q += (double)pr * (double)pr;
    }
    u0[p] = (float)((q - s * s * (1.0 / 50.0)) * (1.0 / 49.0));
}

// ---------------------------------------------------------------------------
// Box filter x3 (separable 7x7, zero pad) per image + global min/max atomics
// ---------------------------------------------------------------------------
__global__ __launch_bounds__(1024)
void gu_box(const float* __restrict__ u0, float* __restrict__ u3,
            unsigned* __restrict__ mnb, unsigned* __restrict__ mxb)
{
    __shared__ float A[HW];   // exactly 64KB
    int b = blockIdx.x, t = threadIdx.x;
    const float* src = u0 + (size_t)b * HW;
    for (int i = t; i < HW; i += 1024) A[i] = src[i];
    __syncthreads();

    float tmp[16];
    for (int pass = 0; pass < 3; ++pass) {
        #pragma unroll
        for (int ii = 0; ii < 16; ++ii) {
            int i = t + ii * 1024;
            int r = i >> 7, c = i & 127;
            float s = 0.f;
            #pragma unroll
            for (int d = -3; d <= 3; ++d) {
                int cc = c + d;
                if (cc >= 0 && cc < 128) s += A[(r << 7) + cc];
            }
            tmp[ii] = s;
        }
        __syncthreads();
        #pragma unroll
        for (int ii = 0; ii < 16; ++ii) A[t + ii * 1024] = tmp[ii];
        __syncthreads();
        #pragma unroll
        for (int ii = 0; ii < 16; ++ii) {
            int i = t + ii * 1024;
            int r = i >> 7, c = i & 127;
            float s = 0.f;
            #pragma unroll
            for (int d = -3; d <= 3; ++d) {
                int rr = r + d;
                if (rr >= 0 && rr < 128) s += A[(rr << 7) + c];
            }
            tmp[ii] = s;
        }
        __syncthreads();
        #pragma unroll
        for (int ii = 0; ii < 16; ++ii) A[t + ii * 1024] = tmp[ii];
        __syncthreads();
    }

    float mn = 3.4e38f, mx = 0.f;
    for (int i = t; i < HW; i += 1024) {
        float v = A[i];
        u3[(size_t)b * HW + i] = v;
        mn = fminf(mn, v); mx = fmaxf(mx, v);
    }
    #pragma unroll
    for (int off = 1; off < 64; off <<= 1) {
        mn = fminf(mn, __shfl_xor(mn, off));
        mx = fmaxf(mx, __shfl_xor(mx, off));
    }
    if ((t & 63) == 0) {   // u >= 0 -> uint order == float order
        atomicMin(mnb, __float_as_uint(mn));
        atomicMax(mxb, __float_as_uint(mx));
    }
}

// ---------------------------------------------------------------------------
// GEMM2: residual = W_conv * relu(a*h+d) + b_conv, scaled by (1-un)*(un<ru)
// Same scalar-W + dbuf structure; BN+ReLU at LDS staging; mask in epilogue.
// ---------------------------------------------------------------------------
__global__ __launch_bounds__(256)
void gu_gemm2(const float* __restrict__ h, const float* __restrict__ Wc,
              const float* __restrict__ bconv, const float* __restrict__ avec,
              const float* __restrict__ dvec, const float* __restrict__ u3,
              const unsigned* __restrict__ mnb, const unsigned* __restrict__ mxb,
              const float* __restrict__ ru, float* __restrict__ outr)
{
    __shared__ float xs[2][KB][NT];
    __shared__ float sa[CC], sd[CC];

    const int t  = threadIdx.x;
    const int tx = t & 63, ty = t >> 6;
    const int tyu = __builtin_amdgcn_readfirstlane(ty);
    const int o0 = blockIdx.y * OT;
    const int n0 = blockIdx.x * NT;
    const int b  = n0 >> 14;
    const int hw0 = n0 & (HW - 1);
    const float* xb = h + ((size_t)b * CC) * HW + hw0;
    const float* Wb = Wc + (size_t)(o0 + tyu * 8) * CC;

    sa[t] = avec[t]; sd[t] = dvec[t];

    float4 pf[4];
    #pragma unroll
    for (int q = 0; q < 4; ++q) {
        int f = t + 256 * q; int k = f >> 7; int co = (f & 127) << 2;
        pf[q] = *(const float4*)(xb + (size_t)k * HW + co);
    }

    float acc[8][8];
    #pragma unroll
    for (int i = 0; i < 8; ++i)
        #pragma unroll
        for (int j = 0; j < 8; ++j) acc[i][j] = 0.f;

    __syncthreads();   // sa/sd ready
    int wb = 0;
    for (int c0 = 0; c0 < CC; c0 += KB) {
        #pragma unroll
        for (int q = 0; q < 4; ++q) {
            int f = t + 256 * q; int k = f >> 7; int co = (f & 127) << 2;
            float a = sa[c0 + k], d = sd[c0 + k];
            float4 v = pf[q];
            v.x = fmaxf(fmaf(a, v.x, d), 0.f);
            v.y = fmaxf(fmaf(a, v.y, d), 0.f);
            v.z = fmaxf(fmaf(a, v.z, d), 0.f);
            v.w = fmaxf(fmaf(a, v.w, d), 0.f);
            *(float4*)&xs[wb][k][co] = v;
        }
        if (c0 + KB < CC) {
            #pragma unroll
            for (int q = 0; q < 4; ++q) {
                int f = t + 256 * q; int k = f >> 7; int co = (f & 127) << 2;
                pf[q] = *(const float4*)(xb + (size_t)(c0 + KB + k) * HW + co);
            }
        }
        __syncthreads();
        #pragma unroll
        for (int half = 0; half < 2; ++half) {
            float4 wq[8];
            #pragma unroll
            for (int i = 0; i < 8; ++i)
                wq[i] = *(const float4*)(Wb + (size_t)i * CC + c0 + half * 4);
            #pragma unroll
            for (int kk = 0; kk < 4; ++kk) {
                int k = half * 4 + kk;
                float4 xa = *(const float4*)&xs[wb][k][tx * 4];
                float4 xc = *(const float4*)&xs[wb][k][256 + tx * 4];
                #pragma unroll
                for (int i = 0; i < 8; ++i) {
                    float w = ((const float*)&wq[i])[kk];
                    acc[i][0] = fmaf(w, xa.x, acc[i][0]);
                    acc[i][1] = fmaf(w, xa.y, acc[i][1]);
                    acc[i][2] = fmaf(w, xa.z, acc[i][2]);
                    acc[i][3] = fmaf(w, xa.w, acc[i][3]);
                    acc[i][4] = fmaf(w, xc.x, acc[i][4]);
                    acc[i][5] = fmaf(w, xc.y, acc[i][5]);
                    acc[i][6] = fmaf(w, xc.z, acc[i][6]);
                    acc[i][7] = fmaf(w, xc.w, acc[i][7]);
                }
            }
        }
        __syncthreads();
        wb ^= 1;
    }

    // epilogue: per-column scale = (un < ru) ? (1-un) : 0, true IEEE division
    float mn = __uint_as_float(*mnb);
    float mx = __uint_as_float(*mxb);
    float den = mx - mn;
    const float* u3b = u3 + (size_t)b * HW + hw0 + tx * 4;
    const float* rub = ru + (size_t)b * HW + hw0 + tx * 4;
    float sc[8];
    #pragma unroll
    for (int j = 0; j < 8; ++j) {
        int off = (j < 4) ? j : 256 + (j - 4);
        float un = (u3b[off] - mn) / den;
        sc[j] = (un < rub[off]) ? (1.f - un) : 0.f;
    }
    #pragma unroll
    for (int i = 0; i < 8; ++i) {
        float bc = bconv[o0 + ty * 8 + i];
        float* op = outr + ((size_t)(b * CC + o0 + ty * 8 + i)) * HW + hw0 + tx * 4;
        *(float4*)op = make_float4((acc[i][0] + bc) * sc[0], (acc[i][1] + bc) * sc[1],
                                   (acc[i][2] + bc) * sc[2], (acc[i][3] + bc) * sc[3]);
        *(float4*)(op + 256) = make_float4((acc[i][4] + bc) * sc[4], (acc[i][5] + bc) * sc[5],
                                           (acc[i][6] + bc) * sc[6], (acc[i][7] + bc) * sc[7]);
    }
}

// ---------------------------------------------------------------------------
extern "C" void kernel_launch(void* const* d_in, const int* in_sizes, int n_in,
                              void* d_out, int out_size, void* d_ws, size_t ws_size,
                              hipStream_t stream)
{
    const float* x     = (const float*)d_in[0];
    const float* Wp    = (const float*)d_in[1];
    const float* gamma = (const float*)d_in[2];
    const float* beta  = (const float*)d_in[3];
    const float* Wc    = (const float*)d_in[4];
    const float* bconv = (const float*)d_in[5];
    const float* Wm    = (const float*)d_in[6];
    const float* Wsd   = (const float*)d_in[7];
    const float* eps1  = (const float*)d_in[8];
    const float* eps50 = (const float*)d_in[9];
    const float* ru    = (const float*)d_in[10];

    float* outr = (float*)d_out;                    // residual: 8*256*128*128
    float* outp = outr + (size_t)33554432;          // prob_x:   8*128*128

    float* ws = (float*)d_ws;
    float* h  = ws;                                  // 33,554,432 floats (134MB)
    const size_t S = (size_t)33554432;
    float*    psum   = ws + S;                       // 256
    float*    psumsq = ws + S + 256;                 // 256
    float*    avec   = ws + S + 512;                 // 256
    float*    dvec   = ws + S + 768;                 // 256
    unsigned* mnb    = (unsigned*)(ws + S + 1024);
    unsigned* mxb    = (unsigned*)(ws + S + 1025);
    float*    u0     = ws + S + 2048;                // 131072
    float*    u3     = u0 + 131072;                  // 131072

    hipMemsetAsync(psum, 0, 512 * sizeof(float), stream);  // psum + psumsq
    hipMemsetAsync(mnb, 0x7f, 4, stream);                   // 0x7f7f7f7f ~ +3.39e38
    hipMemsetAsync(mxb, 0, 4, stream);

    gu_gemm1<<<dim3(256, 8), 256, 0, stream>>>(x, Wp, h, psum, psumsq);
    gu_bnfin<<<1, 256, 0, stream>>>(psum, psumsq, gamma, beta, avec, dvec);
    gu_proj<<<512, 256, 0, stream>>>(h, Wm, Wsd, avec, dvec, eps1, eps50, outp, u0);
    gu_box<<<8, 1024, 0, stream>>>(u0, u3, mnb, mxb);
    gu_gemm2<<<dim3(256, 8), 256, 0, stream>>>(h, Wc, bconv, avec, dvec, u3, mnb, mxb, ru, outr);
}